// Round 1
// baseline (794.817 us; speedup 1.0000x reference)
//
#include <hip/hip_runtime.h>
#include <hip/hip_bf16.h>

typedef __attribute__((ext_vector_type(8))) short short8;
typedef __attribute__((ext_vector_type(4))) float floatx4;

#define MTBL 524288
#define HSTRIDE 72   // bf16 elements per point-row in LDS (64 + 8 pad, keeps 16B align, breaks bank aliasing)

// fp32 -> bf16 round-to-nearest (no tie-to-even correction; bias negligible here)
static __device__ __forceinline__ unsigned int pack2bf(float a, float b) {
    union { float f; unsigned int u; } x, y;
    x.f = a; y.f = b;
    unsigned int lo = (x.u + 0x8000u) >> 16;
    unsigned int hi = (y.u + 0x8000u) & 0xFFFF0000u;
    return lo | hi;
}
static __device__ __forceinline__ short bf1(float a) {
    union { float f; unsigned int u; } x;
    x.f = a;
    return (short)((x.u + 0x8000u) >> 16);
}

__global__ __launch_bounds__(256, 2) void ngp_fused(
    const int* __restrict__ idx,
    const float* __restrict__ tables,
    const float* __restrict__ W1, const float* __restrict__ b1,
    const float* __restrict__ W2, const float* __restrict__ b2,
    const float* __restrict__ W3, const float* __restrict__ b3,
    const float* __restrict__ W4, const float* __restrict__ b4,
    float* __restrict__ out, int tiles_per_wave)
{
    __shared__ float sW1[2048];
    __shared__ float sW2[4096];
    __shared__ float sW3[4096];
    __shared__ float sW4[192];
    __shared__ float sB[200];
    __shared__ __hip_bfloat16 sH[4][16 * HSTRIDE];   // per-wave private h^T scratch

    const int tid = threadIdx.x;
    for (int i = tid; i < 2048; i += 256) sW1[i] = W1[i];
    for (int i = tid; i < 4096; i += 256) sW2[i] = W2[i];
    for (int i = tid; i < 4096; i += 256) sW3[i] = W3[i];
    if (tid < 192) sW4[tid] = W4[tid];
    if (tid < 64)       sB[tid]       = b1[tid];
    else if (tid < 128) sB[tid]       = b2[tid - 64];
    else if (tid < 192) sB[tid]       = b3[tid - 128];
    else if (tid < 195) sB[tid]       = b4[tid - 192];
    __syncthreads();

    const int wave = tid >> 6;
    const int lane = tid & 63;
    const int q = lane >> 4;   // quad within wave
    const int m = lane & 15;   // A-row (hidden unit) / B-col (point)

    // ---- A fragments: A[m][k] = W[k][tile*16+m]  (weights transposed, bf16, in VGPRs) ----
    short8 A1[4], A2[4][2], A3[4][2], A4[2];
#pragma unroll
    for (int t = 0; t < 4; ++t) {
        short8 a;
#pragma unroll
        for (int j = 0; j < 8; ++j)
            a[j] = bf1(sW1[(q * 8 + j) * 64 + t * 16 + m]);
        A1[t] = a;
    }
#pragma unroll
    for (int t = 0; t < 4; ++t)
#pragma unroll
        for (int c = 0; c < 2; ++c) {
            short8 a, a3;
#pragma unroll
            for (int j = 0; j < 8; ++j) {
                a[j]  = bf1(sW2[(c * 32 + q * 8 + j) * 64 + t * 16 + m]);
                a3[j] = bf1(sW3[(c * 32 + q * 8 + j) * 64 + t * 16 + m]);
            }
            A2[t][c] = a;
            A3[t][c] = a3;
        }
#pragma unroll
    for (int c = 0; c < 2; ++c) {
        short8 a;
#pragma unroll
        for (int j = 0; j < 8; ++j)
            a[j] = (m < 3) ? bf1(sW4[(c * 32 + q * 8 + j) * 3 + m]) : (short)0;
        A4[c] = a;
    }

    // ---- bias fragments in C/D layout: row j = t*16 + q*4 + r (broadcast across cols) ----
    floatx4 C1[4], C2[4], C3[4], C4;
#pragma unroll
    for (int t = 0; t < 4; ++t)
#pragma unroll
        for (int r = 0; r < 4; ++r) {
            C1[t][r] = sB[t * 16 + q * 4 + r];
            C2[t][r] = sB[64 + t * 16 + q * 4 + r];
            C3[t][r] = sB[128 + t * 16 + q * 4 + r];
        }
#pragma unroll
    for (int r = 0; r < 4; ++r)
        C4[r] = (q == 0 && r < 3) ? sB[192 + r] : 0.0f;

    __hip_bfloat16* hrow = &sH[wave][m * HSTRIDE];
    const int4*   idx4 = (const int4*)idx;     // idx row = 16 int32 = 4 int4; lane loads int4 #q
    const float2* tbl  = (const float2*)tables;

    const int gw = blockIdx.x * 4 + wave;
    const int tile0 = gw * tiles_per_wave;

    // prologue: idx + gathers for first tile
    int4 iv = idx4[(tile0 * 16 + m) * 4 + q];
    float2 g0 = tbl[(q * 4 + 0) * MTBL + iv.x];
    float2 g1 = tbl[(q * 4 + 1) * MTBL + iv.y];
    float2 g2 = tbl[(q * 4 + 2) * MTBL + iv.z];
    float2 g3 = tbl[(q * 4 + 3) * MTBL + iv.w];

    for (int it = 0; it < tiles_per_wave; ++it) {
        const int pbase = (tile0 + it) * 16;
        const bool more = (it + 1) < tiles_per_wave;

        // pack current x fragment (lane holds features q*8..q*8+7 of point m)
        short8 Bx;
        {
            unsigned int p0 = pack2bf(g0.x, g0.y);
            unsigned int p1 = pack2bf(g1.x, g1.y);
            unsigned int p2 = pack2bf(g2.x, g2.y);
            unsigned int p3 = pack2bf(g3.x, g3.y);
            Bx[0] = (short)(p0 & 0xFFFF); Bx[1] = (short)(p0 >> 16);
            Bx[2] = (short)(p1 & 0xFFFF); Bx[3] = (short)(p1 >> 16);
            Bx[4] = (short)(p2 & 0xFFFF); Bx[5] = (short)(p2 >> 16);
            Bx[6] = (short)(p3 & 0xFFFF); Bx[7] = (short)(p3 >> 16);
        }

        // prefetch next tile's idx (in flight across layer 1-2)
        int4 ivn;
        if (more) ivn = idx4[((pbase + 16) + m) * 4 + q];

        // ---- layer 1: h1^T = W1^T x^T + b1 ----
        floatx4 acc[4];
#pragma unroll
        for (int t = 0; t < 4; ++t)
            acc[t] = __builtin_amdgcn_mfma_f32_16x16x32_bf16(A1[t], Bx, C1[t], 0, 0, 0);

        // ---- transition 1: relu -> bf16 -> LDS (wave-private, no barrier) ----
#pragma unroll
        for (int t = 0; t < 4; ++t) {
            uint2 pk;
            pk.x = pack2bf(fmaxf(acc[t][0], 0.f), fmaxf(acc[t][1], 0.f));
            pk.y = pack2bf(fmaxf(acc[t][2], 0.f), fmaxf(acc[t][3], 0.f));
            *(uint2*)(hrow + t * 16 + q * 4) = pk;
        }
        short8 Bh0 = *(const short8*)(hrow + q * 8);
        short8 Bh1 = *(const short8*)(hrow + 32 + q * 8);

        // ---- layer 2 ----
#pragma unroll
        for (int t = 0; t < 4; ++t) {
            acc[t] = __builtin_amdgcn_mfma_f32_16x16x32_bf16(A2[t][0], Bh0, C2[t], 0, 0, 0);
            acc[t] = __builtin_amdgcn_mfma_f32_16x16x32_bf16(A2[t][1], Bh1, acc[t], 0, 0, 0);
        }

        // issue next tile's gathers now (idx arrived; loads in flight across layers 3-4)
        if (more) {
            g0 = tbl[(q * 4 + 0) * MTBL + ivn.x];
            g1 = tbl[(q * 4 + 1) * MTBL + ivn.y];
            g2 = tbl[(q * 4 + 2) * MTBL + ivn.z];
            g3 = tbl[(q * 4 + 3) * MTBL + ivn.w];
        }

        // ---- transition 2 ----
#pragma unroll
        for (int t = 0; t < 4; ++t) {
            uint2 pk;
            pk.x = pack2bf(fmaxf(acc[t][0], 0.f), fmaxf(acc[t][1], 0.f));
            pk.y = pack2bf(fmaxf(acc[t][2], 0.f), fmaxf(acc[t][3], 0.f));
            *(uint2*)(hrow + t * 16 + q * 4) = pk;
        }
        Bh0 = *(const short8*)(hrow + q * 8);
        Bh1 = *(const short8*)(hrow + 32 + q * 8);

        // ---- layer 3 ----
#pragma unroll
        for (int t = 0; t < 4; ++t) {
            acc[t] = __builtin_amdgcn_mfma_f32_16x16x32_bf16(A3[t][0], Bh0, C3[t], 0, 0, 0);
            acc[t] = __builtin_amdgcn_mfma_f32_16x16x32_bf16(A3[t][1], Bh1, acc[t], 0, 0, 0);
        }

        // ---- transition 3 ----
#pragma unroll
        for (int t = 0; t < 4; ++t) {
            uint2 pk;
            pk.x = pack2bf(fmaxf(acc[t][0], 0.f), fmaxf(acc[t][1], 0.f));
            pk.y = pack2bf(fmaxf(acc[t][2], 0.f), fmaxf(acc[t][3], 0.f));
            *(uint2*)(hrow + t * 16 + q * 4) = pk;
        }
        Bh0 = *(const short8*)(hrow + q * 8);
        Bh1 = *(const short8*)(hrow + 32 + q * 8);

        // ---- layer 4 (single 16-row tile, rows 0..2 valid) ----
        floatx4 o;
        o = __builtin_amdgcn_mfma_f32_16x16x32_bf16(A4[0], Bh0, C4, 0, 0, 0);
        o = __builtin_amdgcn_mfma_f32_16x16x32_bf16(A4[1], Bh1, o, 0, 0, 0);

        if (q == 0) {
            const int pn = pbase + m;
            out[pn * 3 + 0] = o[0];
            out[pn * 3 + 1] = o[1];
            out[pn * 3 + 2] = o[2];
        }
    }
}

extern "C" void kernel_launch(void* const* d_in, const int* in_sizes, int n_in,
                              void* d_out, int out_size, void* d_ws, size_t ws_size,
                              hipStream_t stream) {
    const int*   idx    = (const int*)d_in[0];
    const float* tables = (const float*)d_in[1];
    const float* W1 = (const float*)d_in[2];
    const float* b1 = (const float*)d_in[3];
    const float* W2 = (const float*)d_in[4];
    const float* b2 = (const float*)d_in[5];
    const float* W3 = (const float*)d_in[6];
    const float* b3 = (const float*)d_in[7];
    const float* W4 = (const float*)d_in[8];
    const float* b4 = (const float*)d_in[9];
    float* out = (float*)d_out;

    const int N = in_sizes[0] / 16;           // points
    const int total_tiles = N / 16;           // 16-point MFMA tiles
    const int blocks = 2048;                  // 4 waves/block -> 8192 waves
    const int tiles_per_wave = total_tiles / (blocks * 4);   // = 16 for N=2M

    ngp_fused<<<blocks, 256, 0, stream>>>(idx, tables, W1, b1, W2, b2, W3, b3,
                                          W4, b4, out, tiles_per_wave);
}

// Round 2
// 733.693 us; speedup vs baseline: 1.0833x; 1.0833x over previous
//
#include <hip/hip_runtime.h>
#include <hip/hip_bf16.h>

typedef __attribute__((ext_vector_type(8))) short short8;
typedef __attribute__((ext_vector_type(4))) float floatx4;
typedef __attribute__((ext_vector_type(4))) int int4v;
typedef __attribute__((ext_vector_type(4))) unsigned int uint4v;

#define MTBL 524288
#define HSTRIDE 72   // bf16 elements per point-row in LDS scratch (64+8 pad)

union U4S8 { uint4v u; short8 s; };

// fp32 -> bf16 round-to-nearest
static __device__ __forceinline__ unsigned int pack2bf(float a, float b) {
    union { float f; unsigned int u; } x, y;
    x.f = a; y.f = b;
    unsigned int lo = (x.u + 0x8000u) >> 16;
    unsigned int hi = (y.u + 0x8000u) & 0xFFFF0000u;
    return lo | hi;
}
static __device__ __forceinline__ short bf1(float a) {
    union { float f; unsigned int u; } x;
    x.f = a;
    return (short)((x.u + 0x8000u) >> 16);
}

// ---------------- Kernel A: transpose idx [N][16] -> idxT [16][N] ----------------
// 4 points per thread, register transpose; fully coalesced both directions.
__global__ __launch_bounds__(256) void ngp_transpose(
    const int* __restrict__ idx, int* __restrict__ idxT, int N)
{
    const int t  = blockIdx.x * 256 + threadIdx.x;   // handles points 4t..4t+3
    const int p0 = t * 4;
    const int4v* rows = (const int4v*)idx;           // one point row = 4 int4
    int4v r[4][4];
#pragma unroll
    for (int p = 0; p < 4; ++p)
#pragma unroll
        for (int c = 0; c < 4; ++c)
            r[p][c] = __builtin_nontemporal_load(rows + (size_t)(p0 + p) * 4 + c);
#pragma unroll
    for (int c = 0; c < 4; ++c)
#pragma unroll
        for (int k = 0; k < 4; ++k) {
            const int h = c * 4 + k;
            int4v w;
            w[0] = r[0][c][k]; w[1] = r[1][c][k]; w[2] = r[2][c][k]; w[3] = r[3][c][k];
            __builtin_nontemporal_store(w, (int4v*)(idxT + (size_t)h * N + p0));
        }
}

// ---------------- Kernel B: head-partitioned gather ----------------
// blockIdx&7 -> XCD (round-robin heuristic). XCD x owns heads {2x, 2x+1},
// processed sequentially so the live L2 working set is one 4 MiB head slice.
// idxT reads / xU writes are nontemporal so streams don't evict the table.
// xU[h][n] = uint( bf16(tables[h][i][0]) | bf16(tables[h][i][1])<<16 )
__global__ __launch_bounds__(256) void ngp_gather(
    const int* __restrict__ idxT, const float* __restrict__ tables,
    unsigned int* __restrict__ xU, int N)
{
    const int slot = blockIdx.x >> 3;        // 0..255
    const int base = slot * (N >> 8) + (threadIdx.x << 2);
    const int ITERS = N >> 18;               // (N/256 points)/(256 thr * 4) = 8 for N=2M

#pragma unroll
    for (int hh = 0; hh < 2; ++hh) {
        const int h = ((blockIdx.x & 7) << 1) | hh;
        const int* __restrict__ ih = idxT + (size_t)h * N;
        const float2* __restrict__ th = (const float2*)tables + (size_t)h * MTBL;
        unsigned int* __restrict__ xh = xU + (size_t)h * N;

        int p = base;
        int4v iv = __builtin_nontemporal_load((const int4v*)(ih + p));
        for (int it = 0; it < ITERS; ++it) {
            int4v ivn;
            if (it + 1 < ITERS)
                ivn = __builtin_nontemporal_load((const int4v*)(ih + p + 1024));
            float2 g0 = th[iv[0]];
            float2 g1 = th[iv[1]];
            float2 g2 = th[iv[2]];
            float2 g3 = th[iv[3]];
            uint4v w;
            w[0] = pack2bf(g0.x, g0.y);
            w[1] = pack2bf(g1.x, g1.y);
            w[2] = pack2bf(g2.x, g2.y);
            w[3] = pack2bf(g3.x, g3.y);
            __builtin_nontemporal_store(w, (uint4v*)(xh + p));
            iv = ivn;
            p += 1024;
        }
    }
}

// ---------------- Kernel C: MFMA MLP on contiguous xU ----------------
__global__ __launch_bounds__(256, 2) void ngp_mlp(
    const unsigned int* __restrict__ xU,
    const float* __restrict__ W1, const float* __restrict__ b1,
    const float* __restrict__ W2, const float* __restrict__ b2,
    const float* __restrict__ W3, const float* __restrict__ b3,
    const float* __restrict__ W4, const float* __restrict__ b4,
    float* __restrict__ out, int N, int tiles_per_wave)
{
    __shared__ float sW1[2048];
    __shared__ float sW2[4096];
    __shared__ float sW3[4096];
    __shared__ float sW4[192];
    __shared__ float sB[200];
    __shared__ __hip_bfloat16 sH[4][16 * HSTRIDE];

    const int tid = threadIdx.x;
    for (int i = tid; i < 2048; i += 256) sW1[i] = W1[i];
    for (int i = tid; i < 4096; i += 256) sW2[i] = W2[i];
    for (int i = tid; i < 4096; i += 256) sW3[i] = W3[i];
    if (tid < 192) sW4[tid] = W4[tid];
    if (tid < 64)       sB[tid] = b1[tid];
    else if (tid < 128) sB[tid] = b2[tid - 64];
    else if (tid < 192) sB[tid] = b3[tid - 128];
    else if (tid < 195) sB[tid] = b4[tid - 192];
    __syncthreads();

    const int wave = tid >> 6;
    const int lane = tid & 63;
    const int q = lane >> 4;
    const int m = lane & 15;

    short8 A1[4], A2[4][2], A3[4][2], A4[2];
#pragma unroll
    for (int t = 0; t < 4; ++t) {
        short8 a;
#pragma unroll
        for (int j = 0; j < 8; ++j)
            a[j] = bf1(sW1[(q * 8 + j) * 64 + t * 16 + m]);
        A1[t] = a;
    }
#pragma unroll
    for (int t = 0; t < 4; ++t)
#pragma unroll
        for (int c = 0; c < 2; ++c) {
            short8 a, a3;
#pragma unroll
            for (int j = 0; j < 8; ++j) {
                a[j]  = bf1(sW2[(c * 32 + q * 8 + j) * 64 + t * 16 + m]);
                a3[j] = bf1(sW3[(c * 32 + q * 8 + j) * 64 + t * 16 + m]);
            }
            A2[t][c] = a;
            A3[t][c] = a3;
        }
#pragma unroll
    for (int c = 0; c < 2; ++c) {
        short8 a;
#pragma unroll
        for (int j = 0; j < 8; ++j)
            a[j] = (m < 3) ? bf1(sW4[(c * 32 + q * 8 + j) * 3 + m]) : (short)0;
        A4[c] = a;
    }

    floatx4 C1[4], C2[4], C3[4], C4;
#pragma unroll
    for (int t = 0; t < 4; ++t)
#pragma unroll
        for (int r = 0; r < 4; ++r) {
            C1[t][r] = sB[t * 16 + q * 4 + r];
            C2[t][r] = sB[64 + t * 16 + q * 4 + r];
            C3[t][r] = sB[128 + t * 16 + q * 4 + r];
        }
#pragma unroll
    for (int r = 0; r < 4; ++r)
        C4[r] = (q == 0 && r < 3) ? sB[192 + r] : 0.0f;

    __hip_bfloat16* hrow = &sH[wave][m * HSTRIDE];
    const int gw = blockIdx.x * 4 + wave;
    const int tile0 = gw * tiles_per_wave;

    // B-fragment source: lane (q,m) reads rows 4q..4q+3 of xU at column pbase+m.
    const unsigned int* xr = xU + (size_t)(q * 4) * N + m;

    uint4v cur;
    {
        const int c0 = tile0 * 16;
        cur[0] = xr[c0];
        cur[1] = xr[(size_t)N + c0];
        cur[2] = xr[(size_t)2 * N + c0];
        cur[3] = xr[(size_t)3 * N + c0];
    }

    for (int it = 0; it < tiles_per_wave; ++it) {
        const int pbase = (tile0 + it) * 16;
        const bool more = (it + 1) < tiles_per_wave;

        U4S8 bx; bx.u = cur;
        const short8 Bx = bx.s;

        uint4v nxt;
        if (more) {
            const int cn = pbase + 16;
            nxt[0] = xr[cn];
            nxt[1] = xr[(size_t)N + cn];
            nxt[2] = xr[(size_t)2 * N + cn];
            nxt[3] = xr[(size_t)3 * N + cn];
        }

        // ---- layer 1 ----
        floatx4 acc[4];
#pragma unroll
        for (int t = 0; t < 4; ++t)
            acc[t] = __builtin_amdgcn_mfma_f32_16x16x32_bf16(A1[t], Bx, C1[t], 0, 0, 0);

#pragma unroll
        for (int t = 0; t < 4; ++t) {
            uint2 pk;
            pk.x = pack2bf(fmaxf(acc[t][0], 0.f), fmaxf(acc[t][1], 0.f));
            pk.y = pack2bf(fmaxf(acc[t][2], 0.f), fmaxf(acc[t][3], 0.f));
            *(uint2*)(hrow + t * 16 + q * 4) = pk;
        }
        short8 Bh0 = *(const short8*)(hrow + q * 8);
        short8 Bh1 = *(const short8*)(hrow + 32 + q * 8);

        // ---- layer 2 ----
#pragma unroll
        for (int t = 0; t < 4; ++t) {
            acc[t] = __builtin_amdgcn_mfma_f32_16x16x32_bf16(A2[t][0], Bh0, C2[t], 0, 0, 0);
            acc[t] = __builtin_amdgcn_mfma_f32_16x16x32_bf16(A2[t][1], Bh1, acc[t], 0, 0, 0);
        }

#pragma unroll
        for (int t = 0; t < 4; ++t) {
            uint2 pk;
            pk.x = pack2bf(fmaxf(acc[t][0], 0.f), fmaxf(acc[t][1], 0.f));
            pk.y = pack2bf(fmaxf(acc[t][2], 0.f), fmaxf(acc[t][3], 0.f));
            *(uint2*)(hrow + t * 16 + q * 4) = pk;
        }
        Bh0 = *(const short8*)(hrow + q * 8);
        Bh1 = *(const short8*)(hrow + 32 + q * 8);

        // ---- layer 3 ----
#pragma unroll
        for (int t = 0; t < 4; ++t) {
            acc[t] = __builtin_amdgcn_mfma_f32_16x16x32_bf16(A3[t][0], Bh0, C3[t], 0, 0, 0);
            acc[t] = __builtin_amdgcn_mfma_f32_16x16x32_bf16(A3[t][1], Bh1, acc[t], 0, 0, 0);
        }

#pragma unroll
        for (int t = 0; t < 4; ++t) {
            uint2 pk;
            pk.x = pack2bf(fmaxf(acc[t][0], 0.f), fmaxf(acc[t][1], 0.f));
            pk.y = pack2bf(fmaxf(acc[t][2], 0.f), fmaxf(acc[t][3], 0.f));
            *(uint2*)(hrow + t * 16 + q * 4) = pk;
        }
        Bh0 = *(const short8*)(hrow + q * 8);
        Bh1 = *(const short8*)(hrow + 32 + q * 8);

        // ---- layer 4 ----
        floatx4 o;
        o = __builtin_amdgcn_mfma_f32_16x16x32_bf16(A4[0], Bh0, C4, 0, 0, 0);
        o = __builtin_amdgcn_mfma_f32_16x16x32_bf16(A4[1], Bh1, o, 0, 0, 0);

        if (q == 0) {
            const int pn = pbase + m;
            out[pn * 3 + 0] = o[0];
            out[pn * 3 + 1] = o[1];
            out[pn * 3 + 2] = o[2];
        }

        cur = nxt;
    }
}

// ---------------- Fallback: R1 fused kernel (used only if ws too small) ----------------
__global__ __launch_bounds__(256, 2) void ngp_fused(
    const int* __restrict__ idx,
    const float* __restrict__ tables,
    const float* __restrict__ W1, const float* __restrict__ b1,
    const float* __restrict__ W2, const float* __restrict__ b2,
    const float* __restrict__ W3, const float* __restrict__ b3,
    const float* __restrict__ W4, const float* __restrict__ b4,
    float* __restrict__ out, int tiles_per_wave)
{
    __shared__ float sW1[2048];
    __shared__ float sW2[4096];
    __shared__ float sW3[4096];
    __shared__ float sW4[192];
    __shared__ float sB[200];
    __shared__ __hip_bfloat16 sH[4][16 * HSTRIDE];

    const int tid = threadIdx.x;
    for (int i = tid; i < 2048; i += 256) sW1[i] = W1[i];
    for (int i = tid; i < 4096; i += 256) sW2[i] = W2[i];
    for (int i = tid; i < 4096; i += 256) sW3[i] = W3[i];
    if (tid < 192) sW4[tid] = W4[tid];
    if (tid < 64)       sB[tid] = b1[tid];
    else if (tid < 128) sB[tid] = b2[tid - 64];
    else if (tid < 192) sB[tid] = b3[tid - 128];
    else if (tid < 195) sB[tid] = b4[tid - 192];
    __syncthreads();

    const int wave = tid >> 6;
    const int lane = tid & 63;
    const int q = lane >> 4;
    const int m = lane & 15;

    short8 A1[4], A2[4][2], A3[4][2], A4[2];
#pragma unroll
    for (int t = 0; t < 4; ++t) {
        short8 a;
#pragma unroll
        for (int j = 0; j < 8; ++j)
            a[j] = bf1(sW1[(q * 8 + j) * 64 + t * 16 + m]);
        A1[t] = a;
    }
#pragma unroll
    for (int t = 0; t < 4; ++t)
#pragma unroll
        for (int c = 0; c < 2; ++c) {
            short8 a, a3;
#pragma unroll
            for (int j = 0; j < 8; ++j) {
                a[j]  = bf1(sW2[(c * 32 + q * 8 + j) * 64 + t * 16 + m]);
                a3[j] = bf1(sW3[(c * 32 + q * 8 + j) * 64 + t * 16 + m]);
            }
            A2[t][c] = a;
            A3[t][c] = a3;
        }
#pragma unroll
    for (int c = 0; c < 2; ++c) {
        short8 a;
#pragma unroll
        for (int j = 0; j < 8; ++j)
            a[j] = (m < 3) ? bf1(sW4[(c * 32 + q * 8 + j) * 3 + m]) : (short)0;
        A4[c] = a;
    }

    floatx4 C1[4], C2[4], C3[4], C4;
#pragma unroll
    for (int t = 0; t < 4; ++t)
#pragma unroll
        for (int r = 0; r < 4; ++r) {
            C1[t][r] = sB[t * 16 + q * 4 + r];
            C2[t][r] = sB[64 + t * 16 + q * 4 + r];
            C3[t][r] = sB[128 + t * 16 + q * 4 + r];
        }
#pragma unroll
    for (int r = 0; r < 4; ++r)
        C4[r] = (q == 0 && r < 3) ? sB[192 + r] : 0.0f;

    __hip_bfloat16* hrow = &sH[wave][m * HSTRIDE];
    const int4*   idx4 = (const int4*)idx;
    const float2* tbl  = (const float2*)tables;

    const int gw = blockIdx.x * 4 + wave;
    const int tile0 = gw * tiles_per_wave;

    int4 iv = idx4[(tile0 * 16 + m) * 4 + q];
    float2 g0 = tbl[(q * 4 + 0) * MTBL + iv.x];
    float2 g1 = tbl[(q * 4 + 1) * MTBL + iv.y];
    float2 g2 = tbl[(q * 4 + 2) * MTBL + iv.z];
    float2 g3 = tbl[(q * 4 + 3) * MTBL + iv.w];

    for (int it = 0; it < tiles_per_wave; ++it) {
        const int pbase = (tile0 + it) * 16;
        const bool more = (it + 1) < tiles_per_wave;

        short8 Bx;
        {
            unsigned int p0 = pack2bf(g0.x, g0.y);
            unsigned int p1 = pack2bf(g1.x, g1.y);
            unsigned int p2 = pack2bf(g2.x, g2.y);
            unsigned int p3 = pack2bf(g3.x, g3.y);
            Bx[0] = (short)(p0 & 0xFFFF); Bx[1] = (short)(p0 >> 16);
            Bx[2] = (short)(p1 & 0xFFFF); Bx[3] = (short)(p1 >> 16);
            Bx[4] = (short)(p2 & 0xFFFF); Bx[5] = (short)(p2 >> 16);
            Bx[6] = (short)(p3 & 0xFFFF); Bx[7] = (short)(p3 >> 16);
        }

        int4 ivn;
        if (more) ivn = idx4[((pbase + 16) + m) * 4 + q];

        floatx4 acc[4];
#pragma unroll
        for (int t = 0; t < 4; ++t)
            acc[t] = __builtin_amdgcn_mfma_f32_16x16x32_bf16(A1[t], Bx, C1[t], 0, 0, 0);

#pragma unroll
        for (int t = 0; t < 4; ++t) {
            uint2 pk;
            pk.x = pack2bf(fmaxf(acc[t][0], 0.f), fmaxf(acc[t][1], 0.f));
            pk.y = pack2bf(fmaxf(acc[t][2], 0.f), fmaxf(acc[t][3], 0.f));
            *(uint2*)(hrow + t * 16 + q * 4) = pk;
        }
        short8 Bh0 = *(const short8*)(hrow + q * 8);
        short8 Bh1 = *(const short8*)(hrow + 32 + q * 8);

#pragma unroll
        for (int t = 0; t < 4; ++t) {
            acc[t] = __builtin_amdgcn_mfma_f32_16x16x32_bf16(A2[t][0], Bh0, C2[t], 0, 0, 0);
            acc[t] = __builtin_amdgcn_mfma_f32_16x16x32_bf16(A2[t][1], Bh1, acc[t], 0, 0, 0);
        }

        if (more) {
            g0 = tbl[(q * 4 + 0) * MTBL + ivn.x];
            g1 = tbl[(q * 4 + 1) * MTBL + ivn.y];
            g2 = tbl[(q * 4 + 2) * MTBL + ivn.z];
            g3 = tbl[(q * 4 + 3) * MTBL + ivn.w];
        }

#pragma unroll
        for (int t = 0; t < 4; ++t) {
            uint2 pk;
            pk.x = pack2bf(fmaxf(acc[t][0], 0.f), fmaxf(acc[t][1], 0.f));
            pk.y = pack2bf(fmaxf(acc[t][2], 0.f), fmaxf(acc[t][3], 0.f));
            *(uint2*)(hrow + t * 16 + q * 4) = pk;
        }
        Bh0 = *(const short8*)(hrow + q * 8);
        Bh1 = *(const short8*)(hrow + 32 + q * 8);

#pragma unroll
        for (int t = 0; t < 4; ++t) {
            acc[t] = __builtin_amdgcn_mfma_f32_16x16x32_bf16(A3[t][0], Bh0, C3[t], 0, 0, 0);
            acc[t] = __builtin_amdgcn_mfma_f32_16x16x32_bf16(A3[t][1], Bh1, acc[t], 0, 0, 0);
        }

#pragma unroll
        for (int t = 0; t < 4; ++t) {
            uint2 pk;
            pk.x = pack2bf(fmaxf(acc[t][0], 0.f), fmaxf(acc[t][1], 0.f));
            pk.y = pack2bf(fmaxf(acc[t][2], 0.f), fmaxf(acc[t][3], 0.f));
            *(uint2*)(hrow + t * 16 + q * 4) = pk;
        }
        Bh0 = *(const short8*)(hrow + q * 8);
        Bh1 = *(const short8*)(hrow + 32 + q * 8);

        floatx4 o;
        o = __builtin_amdgcn_mfma_f32_16x16x32_bf16(A4[0], Bh0, C4, 0, 0, 0);
        o = __builtin_amdgcn_mfma_f32_16x16x32_bf16(A4[1], Bh1, o, 0, 0, 0);

        if (q == 0) {
            const int pn = pbase + m;
            out[pn * 3 + 0] = o[0];
            out[pn * 3 + 1] = o[1];
            out[pn * 3 + 2] = o[2];
        }
    }
}

extern "C" void kernel_launch(void* const* d_in, const int* in_sizes, int n_in,
                              void* d_out, int out_size, void* d_ws, size_t ws_size,
                              hipStream_t stream) {
    const int*   idx    = (const int*)d_in[0];
    const float* tables = (const float*)d_in[1];
    const float* W1 = (const float*)d_in[2];
    const float* b1 = (const float*)d_in[3];
    const float* W2 = (const float*)d_in[4];
    const float* b2 = (const float*)d_in[5];
    const float* W3 = (const float*)d_in[6];
    const float* b3 = (const float*)d_in[7];
    const float* W4 = (const float*)d_in[8];
    const float* b4 = (const float*)d_in[9];
    float* out = (float*)d_out;

    const int N = in_sizes[0] / 16;            // points (2,097,152)
    const int total_tiles = N / 16;

    const size_t idxT_bytes = (size_t)16 * N * 4;   // 128 MiB
    const size_t xU_bytes   = (size_t)16 * N * 4;   // 128 MiB
    const size_t need = idxT_bytes + xU_bytes;

    if (ws_size >= need) {
        int*          idxT = (int*)d_ws;
        unsigned int* xU   = (unsigned int*)((char*)d_ws + idxT_bytes);

        // A: transpose idx (4 points/thread)
        ngp_transpose<<<N / 1024, 256, 0, stream>>>(idx, idxT, N);
        // B: head-partitioned gather, 2048 blocks = 8 blocks/CU, all co-resident
        ngp_gather<<<2048, 256, 0, stream>>>(idxT, tables, xU, N);
        // C: MFMA MLP
        const int blocks = 2048;
        const int tiles_per_wave = total_tiles / (blocks * 4);
        ngp_mlp<<<blocks, 256, 0, stream>>>(xU, W1, b1, W2, b2, W3, b3, W4, b4,
                                            out, N, tiles_per_wave);
    } else {
        const int blocks = 2048;
        const int tiles_per_wave = total_tiles / (blocks * 4);
        ngp_fused<<<blocks, 256, 0, stream>>>(idx, tables, W1, b1, W2, b2, W3, b3,
                                              W4, b4, out, tiles_per_wave);
    }
}